// Round 6
// baseline (256.397 us; speedup 1.0000x reference)
//
#include <hip/hip_runtime.h>

#define TT 512
#define LL 64
#define BB 16
#define NN 20
#define DTC 0.01f
#define NOISEC 1e-3f
#define LN2C 0.69314718056f
#define QROW 12              // qrT row stride in floats (48B, 16B-aligned)
#define NROWS 80             // qrevPad128 flat 640 = 80 rows of 8
#define QSP 544              // skewed Q buffer (max idx SK(511)=539)

// skew: +4 dwords per 32-block; octets never cross a block (starts mult of 8)
#define SK(t) ((t) + 4 * (((t) >> 5) & 7))

// ws[0..63] = rowsum(pathloss), ws[64..127] = diag(pathloss)
__global__ void prep_kernel(const float* __restrict__ pathloss, float* __restrict__ ws) {
    int l = threadIdx.x;  // 64 threads
    float s = 0.f;
    #pragma unroll
    for (int j = 0; j < LL; ++j) s += pathloss[l * LL + j];
    ws[l] = s;
    ws[LL + l] = pathloss[l * LL + l];
}

// One octet of 8 m's at window phase PH (k&1). Slot indices static after
// unroll: acc[r] += Q[m]*W[(r-tau)&15], fresh lands in slot (15-tau)&15.
template<int PH>
__device__ __forceinline__ void octet(const float* frow, const float* qrow,
                                      float (&W)[16], float (&acc)[16]) {
    const float4 fa = *(const float4*)frow;
    const float4 fb = *(const float4*)(frow + 4);
    const float4 qa = *(const float4*)qrow;
    const float4 qb = *(const float4*)(qrow + 4);
    const float qm[8] = {qa.x, qa.y, qa.z, qa.w, qb.x, qb.y, qb.z, qb.w};
    const float fr[8] = {fa.x, fa.y, fa.z, fa.w, fb.x, fb.y, fb.z, fb.w};
    #pragma unroll
    for (int i = 0; i < 8; ++i) {
        const int tt = 8 * PH + i;
        #pragma unroll
        for (int r = 0; r < 16; ++r)
            acc[r] = fmaf(qm[i], W[(r - tt + 16) & 15], acc[r]);
        W[(15 - tt) & 15] = fr[i];
    }
}

// One slot: quarter q (t in [128q,128q+128)), m-half h (m in
// [64(q+1)h, 64(q+1)(h+1))). g = t-group (16 outputs), lam = 8-way m-split.
// Computes, split-tree reduces over lam, ds_adds DT-scaled sums into Qw.
__device__ __forceinline__ void slot(const float* qrTb, const float* Qr,
                                     float* Qw, int q, int h, int g, int lam) {
    const int T0 = 128 * q + 16 * g;
    const int M0 = 64 * (q + 1) * h + 8 * (q + 1) * lam;
    const int vr = (128 + T0 - M0) >> 3;          // window base row
    float W[16], acc[16];
    {   // W[x] = qrevPad[VB+x]: row vr holds x=7..0, row vr+1 x=15..8
        const float* qi = qrTb + vr * QROW;
        const float4 a0 = *(const float4*)(qi);
        const float4 a1 = *(const float4*)(qi + 4);
        const float4 a2 = *(const float4*)(qi + QROW);
        const float4 a3 = *(const float4*)(qi + QROW + 4);
        W[7]  = a0.x; W[6]  = a0.y; W[5]  = a0.z; W[4]  = a0.w;
        W[3]  = a1.x; W[2]  = a1.y; W[1]  = a1.z; W[0]  = a1.w;
        W[15] = a2.x; W[14] = a2.y; W[13] = a2.z; W[12] = a2.w;
        W[11] = a3.x; W[10] = a3.y; W[9]  = a3.z; W[8]  = a3.w;
    }
    #pragma unroll
    for (int r = 0; r < 16; ++r) acc[r] = 0.f;

    const int octs = q + 1;                       // wave-uniform trip count
    const float* frow = qrTb + (vr - 1) * QROW;   // fresh row for k=0
    int mb = M0;
    for (int j = 0; j < (octs >> 1); ++j) {       // parity pairs
        octet<0>(frow, Qr + SK(mb), W, acc); frow -= QROW; mb += 8;
        octet<1>(frow, Qr + SK(mb), W, acc); frow -= QROW; mb += 8;
    }
    if (octs & 1)                                 // odd count only at even q ->
        octet<0>(frow, Qr + SK(mb), W, acc);      // tail parity always 0

    // split-tree reduction over lam (masks 1,2,4): each lane ends with 2 t's
    float o1[8], o2[4], o3[2];
    #pragma unroll
    for (int u = 0; u < 8; ++u) {
        float snd = (lam & 1) ? acc[u] : acc[u + 8];
        float kp  = (lam & 1) ? acc[u + 8] : acc[u];
        o1[u] = kp + __shfl_xor(snd, 1, 64);
    }
    #pragma unroll
    for (int u = 0; u < 4; ++u) {
        float snd = (lam & 2) ? o1[u] : o1[u + 4];
        float kp  = (lam & 2) ? o1[u + 4] : o1[u];
        o2[u] = kp + __shfl_xor(snd, 2, 64);
    }
    #pragma unroll
    for (int u = 0; u < 2; ++u) {
        float snd = (lam & 4) ? o2[u] : o2[u + 2];
        float kp  = (lam & 4) ? o2[u + 2] : o2[u];
        o3[u] = kp + __shfl_xor(snd, 4, 64);
    }
    const int tl = ((lam & 1) << 3) | (((lam >> 1) & 1) << 2) | (((lam >> 2) & 1) << 1);
    const int sa = SK(T0 + tl);                   // tl even -> sa, sa+1 same block
    atomicAdd(Qw + sa,     o3[0] * DTC);          // two owner waves combine here
    atomicAdd(Qw + sa + 1, o3[1] * DTC);
}

// One block per channel c = b*64+l. 256 threads = 4 waves. Wave v owns
// t-quarters {v, 3-v} with complementary m-halves -> 5 octet-trips per wave
// per step, uniform across waves (placement-proof balance). Triangle skipped:
// quarter q only sums m < 128(q+1); 128-zero pad handles the in-rect residue.
// qrT[j][p] = qrevPad128[8j+7-p]; rows 0..15 zero, rows 16..79 = q_n data.
// Q double-buffered (ping-pong) with ds_add combine; 2 barriers per step.
__global__ __launch_bounds__(256) void outage_kernel(
    const float* __restrict__ powers,
    const float* __restrict__ ws,
    float* __restrict__ out)
{
    __shared__ float Qb[2][QSP];
    __shared__ float qrT[NROWS * QROW];

    const int tid  = threadIdx.x;
    const int wave = tid >> 6;
    const int lane = tid & 63;
    const int g    = lane >> 3;
    const int lam  = lane & 7;
    const int c = blockIdx.x;
    const int b = c >> 6;
    const int l = c & 63;

    const float rs = ws[l];
    const float dg = ws[LL + l];
    const float dsum = rs - dg;

    const int tau0 = tid;
    const int tau1 = tid + 256;
    const float p2a = exp2f(tau0 * DTC);
    const float p2b = exp2f(tau1 * DTC);
    const float p1a = p2a - 1.f;
    const float p1b = p2b - 1.f;

    // ---- init: zero pad rows, Q0 into Qb[0], zero Qb[1], fill qrT(n=1) ----
    if (tid < 128) qrT[(tid >> 3) * QROW + (tid & 7)] = 0.f;   // rows 0..15
    {
        float p  = powers[(b * NN + 0) * LL + l];
        float s0 = dg * p / (p * dsum + NOISEC);
        Qb[0][SK(tau0)] = 1.f - expf(-p1a * s0);
        Qb[0][SK(tau1)] = 1.f - expf(-p1b * s0);
    }
    ((float2*)Qb[1])[tid] = make_float2(0.f, 0.f);
    if (tid < QSP - TT) Qb[1][TT + tid] = 0.f;
    {
        float p = powers[(b * NN + 1) * LL + l];
        float s = dg * p / (p * dsum + NOISEC);
        qrT[((639 - tau0) >> 3) * QROW + (tau0 & 7)] = expf(-p1a * s) * p2a * s * LN2C;
        qrT[((639 - tau1) >> 3) * QROW + (tau1 & 7)] = expf(-p1b * s) * p2b * s * LN2C;
    }
    __syncthreads();

    float lossCh = 0.f;
    if (tid == 0) {
        lossCh = 1.f + powers[(b * NN + 0) * LL + l]
               + (powers[(b * NN + 1) * LL + l] + 1.f) * Qb[0][SK(TT - 1)];
    }

    for (int n = 1; n < NN; ++n) {
        const int rb = (n - 1) & 1, wb = n & 1;
        const float* Qr = Qb[rb];
        float* Qw = Qb[wb];

        slot(qrT, Qr, Qw, wave, 0, g, lam);       // quarter v, low m-half
        slot(qrT, Qr, Qw, 3 - wave, 1, g, lam);   // quarter 3-v, high m-half
        __syncthreads();

        // write phase: zero the just-read buffer (becomes next write buf),
        // refill qrT for step n+1
        {
            float* Qz = Qb[rb];
            ((float2*)Qz)[tid] = make_float2(0.f, 0.f);
            if (tid < QSP - TT) Qz[TT + tid] = 0.f;
        }
        if (n < NN - 1) {
            float p = powers[(b * NN + n + 1) * LL + l];
            float s = dg * p / (p * dsum + NOISEC);
            qrT[((639 - tau0) >> 3) * QROW + (tau0 & 7)] = expf(-p1a * s) * p2a * s * LN2C;
            qrT[((639 - tau1) >> 3) * QROW + (tau1 & 7)] = expf(-p1b * s) * p2b * s * LN2C;
        }
        __syncthreads();

        if (tid == 0) {
            float wgt = (n < NN - 1) ? (powers[(b * NN + n + 1) * LL + l] + 1.f)
                                     : 1.f;       // LAM term for n = 19
            lossCh += wgt * Qw[SK(TT - 1)];
        }
    }

    if (tid == 0) atomicAdd(out, lossCh);
}

extern "C" void kernel_launch(void* const* d_in, const int* in_sizes, int n_in,
                              void* d_out, int out_size, void* d_ws, size_t ws_size,
                              hipStream_t stream) {
    const float* pathloss = (const float*)d_in[0];
    const float* powers   = (const float*)d_in[1];
    float* outp = (float*)d_out;
    float* ws   = (float*)d_ws;

    hipMemsetAsync(d_out, 0, sizeof(float) * out_size, stream);
    prep_kernel<<<1, 64, 0, stream>>>(pathloss, ws);
    outage_kernel<<<BB * LL, 256, 0, stream>>>(powers, ws, outp);
}

// Round 8
// 92.688 us; speedup vs baseline: 2.7662x; 2.7662x over previous
//
#include <hip/hip_runtime.h>

#define LL 64
#define NN 20
#define DTC 0.01f
#define NOISEC 1e-3f
#define LN2C 0.69314718056f

typedef __attribute__((ext_vector_type(8))) short short8x;
typedef __attribute__((ext_vector_type(4))) float f32x4;

// ws[0..63] = rowsum(pathloss), ws[64..127] = diag(pathloss)
__global__ void prep_kernel(const float* __restrict__ pathloss, float* __restrict__ ws) {
    int l = threadIdx.x;  // 64 threads
    float s = 0.f;
    #pragma unroll
    for (int j = 0; j < LL; ++j) s += pathloss[l * LL + j];
    ws[l] = s;
    ws[LL + l] = pathloss[l * LL + l];
}

// pack two floats to bf16x2 with round-to-nearest-even (manual, no HIP types)
__device__ __forceinline__ unsigned bf16r(float x) {
    union { float f; unsigned u; } a; a.f = x;
    return (a.u + (0x7fffu + ((a.u >> 16) & 1u))) >> 16;
}
__device__ __forceinline__ unsigned pk_bf16(float x, float y) {
    return bf16r(x) | (bf16r(y) << 16);
}

// One wave (64 thr) per channel c = b*64+l. NO barriers anywhere.
// Block-Toeplitz MFMA: Qn[32I+i] = sum_d sum_k G_d[i][k] * Qsrc[32(I-d)+k],
// G_d[i][k] = g(32d+i-k), g(delta) = DT*q_n[511-delta] (delta>=0, else 0).
// Natural table r[tau] = DT*q_n(tau); A-frag lane(m=lane&15,q=lane>>4)[j]
// = r[511-32d-16Mt-m+8q + j] -> per-lane start misaligned by (7-m)&7, so the
// row is stored 8x pre-shifted: copy k, pos w holds r[w+k]; lane reads copy
// (7-m)&7 at an 8-aligned start -> every A/B access is one ds_read_b128.
// B-frag lane(n=lane&15,q)[j] = Qsrc[32(n-d)+8q+j], zero-prefix handles n<d.
// C/D: lane(col=lane&15,quad) reg r -> Qn[32col+16Mt+4quad+r] (m89 layout).
__global__ __launch_bounds__(64) void outage_kernel(
    const float* __restrict__ powers,
    const float* __restrict__ ws,
    float* __restrict__ out)
{
    __shared__ __align__(16) unsigned short gt[2][8][544];  // 8 shifted copies, ping-pong
    __shared__ __align__(16) unsigned short Qb[2][1024];    // [0,512)=zeros, [512,1024)=data

    const int lane = threadIdx.x;
    const int c = blockIdx.x, b = c >> 6, l = c & 63;
    const int nh = lane & 15;          // MFMA m / n index
    const int qd = lane >> 4;          // MFMA quad (k-group)

    const float dg = ws[LL + l];
    const float dsum = ws[l] - dg;

    // per-lane time constants, tau = 8*lane + u
    float P2[8], P1[8];
    #pragma unroll
    for (int u = 0; u < 8; ++u) {
        P2[u] = exp2f((8 * lane + u) * DTC);
        P1[u] = P2[u] - 1.f;
    }

    // zero Q prefixes (1 KiB each) and gt tails [512,544) of both buffers
    *((uint4*)&Qb[0][0] + lane) = uint4{0u, 0u, 0u, 0u};
    *((uint4*)&Qb[1][0] + lane) = uint4{0u, 0u, 0u, 0u};
    {
        const int bb = lane >> 5, w = lane & 31;
        #pragma unroll
        for (int k = 0; k < 8; ++k) gt[bb][k][512 + w] = 0;
    }

    // Q0(tau) = 1 - exp(-(2^{tau*DT}-1)*s0), bf16 into Qb[0]
    const float p0 = powers[(b * NN + 0) * LL + l];
    const float s0 = dg * p0 / (p0 * dsum + NOISEC);
    float q7;
    {
        float v[8];
        #pragma unroll
        for (int u = 0; u < 8; ++u) v[u] = 1.f - expf(-P1[u] * s0);
        q7 = v[7];                                  // lane 63: Q0[511]
        uint4 d4 = { pk_bf16(v[0], v[1]), pk_bf16(v[2], v[3]),
                     pk_bf16(v[4], v[5]), pk_bf16(v[6], v[7]) };
        *(uint4*)&Qb[0][512 + 8 * lane] = d4;
    }

    const float p1v = powers[(b * NN + 1) * LL + l];
    float lossCh = 1.f + p0 + (p1v + 1.f) * q7;     // only lane 63's is used

    // fill the 8 shifted copies of r[tau] = DT*q_n(tau) for step n into buf
    auto fill_g = [&](int buf, float p) {
        float s  = dg * p / (p * dsum + NOISEC);
        float cm = s * LN2C * DTC;
        unsigned F[8];                               // F[0..3] own pairs, F[4..7] neighbor
        #pragma unroll
        for (int w = 0; w < 4; ++w) {
            float a  = expf(-P1[2 * w] * s) * P2[2 * w] * cm;
            float bb = expf(-P1[2 * w + 1] * s) * P2[2 * w + 1] * cm;
            F[w] = pk_bf16(a, bb);
        }
        #pragma unroll
        for (int w = 0; w < 4; ++w) {
            unsigned t = (unsigned)__shfl_down((int)F[w], 1, 64);
            F[4 + w] = (lane == 63) ? 0u : t;       // tau >= 512 -> 0
        }
        unsigned E[7];                               // odd-phase pairs
        #pragma unroll
        for (int j = 0; j < 7; ++j) E[j] = (F[j] >> 16) | (F[j + 1] << 16);
        #pragma unroll
        for (int k = 0; k < 8; ++k) {               // copy k pos 8L+w holds r[8L+w+k]
            uint4 d4;
            if ((k & 1) == 0) d4 = uint4{F[k / 2], F[k / 2 + 1], F[k / 2 + 2], F[k / 2 + 3]};
            else              d4 = uint4{E[k / 2], E[k / 2 + 1], E[k / 2 + 2], E[k / 2 + 3]};
            *(uint4*)&gt[buf][k][8 * lane] = d4;
        }
    };
    fill_g(1, p1v);                                 // g-table for step n=1

    const int kk    = (7 - nh) & 7;                 // this lane's copy index
    const int baseA = 511 - nh + 8 * qd - kk;       // == 0 mod 8 (16B aligned)
    const int baseB = 512 + 32 * nh + 8 * qd;
    const int dstw  = 512 + 32 * nh + 4 * qd;       // +16 for M-tile 1

    for (int n = 1; n < NN; ++n) {
        const unsigned short* psrc = &Qb[(n + 1) & 1][0];   // == (n-1)&1
        const unsigned short* pg   = &gt[n & 1][kk][0];
        unsigned short* pdst       = &Qb[n & 1][0];

        f32x4 acc0 = {0.f, 0.f, 0.f, 0.f};
        f32x4 acc1 = {0.f, 0.f, 0.f, 0.f};
        #pragma unroll
        for (int d = 0; d < 16; ++d) {
            short8x bf = *(const short8x*)&psrc[baseB - 32 * d];
            short8x a0 = *(const short8x*)&pg[baseA - 32 * d];
            short8x a1 = *(const short8x*)&pg[baseA - 32 * d - 16];
            acc0 = __builtin_amdgcn_mfma_f32_16x16x32_bf16(a0, bf, acc0, 0, 0, 0);
            acc1 = __builtin_amdgcn_mfma_f32_16x16x32_bf16(a1, bf, acc1, 0, 0, 0);
        }

        // write Qn (bf16): lane holds rows 4qd..4qd+3 of both M-tiles, col nh
        *(uint2*)&pdst[dstw]      = uint2{pk_bf16(acc0.x, acc0.y), pk_bf16(acc0.z, acc0.w)};
        *(uint2*)&pdst[dstw + 16] = uint2{pk_bf16(acc1.x, acc1.y), pk_bf16(acc1.z, acc1.w)};

        // loss tap: lane 63 acc1.w == Qn[511] (row 31, col 15), fp32 precision
        if (n < NN - 1) {
            float pn = powers[(b * NN + n + 1) * LL + l];
            lossCh += (pn + 1.f) * acc1.w;
            fill_g((n + 1) & 1, pn);
        } else {
            lossCh += acc1.w;                        // LAM term, n = 19
        }
    }

    if (lane == 63) atomicAdd(out, lossCh);
}

extern "C" void kernel_launch(void* const* d_in, const int* in_sizes, int n_in,
                              void* d_out, int out_size, void* d_ws, size_t ws_size,
                              hipStream_t stream) {
    const float* pathloss = (const float*)d_in[0];
    const float* powers   = (const float*)d_in[1];
    float* outp = (float*)d_out;
    float* ws   = (float*)d_ws;

    (void)hipMemsetAsync(d_out, 0, sizeof(float) * out_size, stream);
    prep_kernel<<<1, 64, 0, stream>>>(pathloss, ws);
    outage_kernel<<<16 * LL, 64, 0, stream>>>(powers, ws, outp);
}

// Round 9
// 89.801 us; speedup vs baseline: 2.8552x; 1.0321x over previous
//
#include <hip/hip_runtime.h>

#define LL 64
#define NN 20
#define DTC 0.01f
#define NOISEC 1e-3f
#define LN2C 0.69314718056f

typedef __attribute__((ext_vector_type(8))) short short8x;
typedef __attribute__((ext_vector_type(4))) float f32x4;

// pack two floats to bf16x2 with round-to-nearest-even (manual, no HIP types)
__device__ __forceinline__ unsigned bf16r(float x) {
    union { float f; unsigned u; } a; a.f = x;
    return (a.u + (0x7fffu + ((a.u >> 16) & 1u))) >> 16;
}
__device__ __forceinline__ unsigned pk_bf16(float x, float y) {
    return bf16r(x) | (bf16r(y) << 16);
}

// One wave (64 thr) per channel c = b*64+l. NO barriers anywhere.
// Block-Toeplitz MFMA: Qn[32I+i] = sum_d sum_k G_d[i][k] * Qsrc[32(I-d)+k],
// G_d[i][k] = g(32d+i-k), g(delta) = DT*q_n[511-delta] (delta>=0, else 0).
// gt copy kk, pos w holds r[w+kk] (r[tau] = DT*q_n(tau), zero tail) so every
// A-fragment read is one aligned ds_read_b128; B likewise (Q zero-prefix).
// R9: prep folded in (butterfly rowsum), all 48 operand b128s prefetched to
// registers, 4 independent MFMA chains, powers-load pipelined one step ahead,
// fill_g hoisted between prefetch and MFMA chain (independent gt buffer).
__global__ __launch_bounds__(64, 1) void outage_kernel(
    const float* __restrict__ pathloss,
    const float* __restrict__ powers,
    float* __restrict__ out)
{
    __shared__ __align__(16) unsigned short gt[2][8][544];  // 8 shifted copies, ping-pong
    __shared__ __align__(16) unsigned short Qb[2][1024];    // [0,512)=zeros, [512,1024)=data

    const int lane = threadIdx.x;
    const int c = blockIdx.x, b = c >> 6, l = c & 63;
    const int nh = lane & 15;          // MFMA m / n index
    const int qd = lane >> 4;          // MFMA quad (k-group)

    // ---- inline prep: rowsum + diag of pathloss row l (coalesced) ----
    const float pl = pathloss[l * LL + lane];
    float rs = pl;
    #pragma unroll
    for (int mk = 1; mk < 64; mk <<= 1) rs += __shfl_xor(rs, mk, 64);
    const float dg   = __shfl(pl, l, 64);
    const float dsum = rs - dg;

    // per-lane time constants, tau = 8*lane + u
    float P2[8], P1[8];
    #pragma unroll
    for (int u = 0; u < 8; ++u) {
        P2[u] = exp2f((8 * lane + u) * DTC);
        P1[u] = P2[u] - 1.f;
    }

    // zero Q prefixes (1 KiB each) and gt tails [512,544) of both buffers
    *((uint4*)&Qb[0][0] + lane) = uint4{0u, 0u, 0u, 0u};
    *((uint4*)&Qb[1][0] + lane) = uint4{0u, 0u, 0u, 0u};
    {
        const int bb = lane >> 5, w = lane & 31;
        #pragma unroll
        for (int k = 0; k < 8; ++k) gt[bb][k][512 + w] = 0;
    }

    // Q0(tau) = 1 - exp(-(2^{tau*DT}-1)*s0), bf16 into Qb[0]
    const float p0 = powers[(b * NN + 0) * LL + l];
    const float s0 = dg * p0 / (p0 * dsum + NOISEC);
    float q7;
    {
        float v[8];
        #pragma unroll
        for (int u = 0; u < 8; ++u) v[u] = 1.f - expf(-P1[u] * s0);
        q7 = v[7];                                  // lane 63: Q0[511]
        uint4 d4 = { pk_bf16(v[0], v[1]), pk_bf16(v[2], v[3]),
                     pk_bf16(v[4], v[5]), pk_bf16(v[6], v[7]) };
        *(uint4*)&Qb[0][512 + 8 * lane] = d4;
    }

    const float p1v = powers[(b * NN + 1) * LL + l];
    float lossCh = 1.f + p0 + (p1v + 1.f) * q7;     // only lane 63's is used

    // fill the 8 shifted copies of r[tau] = DT*q_n(tau) for a step into buf
    auto fill_g = [&](int buf, float p) {
        float s  = dg * p / (p * dsum + NOISEC);
        float cm = s * LN2C * DTC;
        unsigned F[8];                               // F[0..3] own pairs, F[4..7] neighbor
        #pragma unroll
        for (int w = 0; w < 4; ++w) {
            float a  = expf(-P1[2 * w] * s) * P2[2 * w] * cm;
            float bb = expf(-P1[2 * w + 1] * s) * P2[2 * w + 1] * cm;
            F[w] = pk_bf16(a, bb);
        }
        #pragma unroll
        for (int w = 0; w < 4; ++w) {
            unsigned t = (unsigned)__shfl_down((int)F[w], 1, 64);
            F[4 + w] = (lane == 63) ? 0u : t;       // tau >= 512 -> 0
        }
        unsigned E[7];                               // odd-phase pairs
        #pragma unroll
        for (int j = 0; j < 7; ++j) E[j] = (F[j] >> 16) | (F[j + 1] << 16);
        #pragma unroll
        for (int k = 0; k < 8; ++k) {               // copy k pos 8L+w holds r[8L+w+k]
            uint4 d4;
            if ((k & 1) == 0) d4 = uint4{F[k / 2], F[k / 2 + 1], F[k / 2 + 2], F[k / 2 + 3]};
            else              d4 = uint4{E[k / 2], E[k / 2 + 1], E[k / 2 + 2], E[k / 2 + 3]};
            *(uint4*)&gt[buf][k][8 * lane] = d4;
        }
    };
    fill_g(1, p1v);                                 // g-table for step n=1

    const int kk    = (7 - nh) & 7;                 // this lane's copy index
    const int baseA = 511 - nh + 8 * qd - kk;       // == 0 mod 8 (16B aligned)
    const int baseB = 512 + 32 * nh + 8 * qd;
    const int dstw  = 512 + 32 * nh + 4 * qd;       // +16 for M-tile 1

    float pnext = powers[(b * NN + 2) * LL + l];    // pw[n+1] entering n=1

    for (int n = 1; n < NN; ++n) {
        const unsigned short* psrc = &Qb[(n + 1) & 1][0];   // == (n-1)&1
        const unsigned short* pg   = &gt[n & 1][kk][0];
        unsigned short* pdst       = &Qb[n & 1][0];

        // issue next-next power load early (lands during this step's work)
        float pfut = 0.f;
        if (n <= NN - 3) pfut = powers[(b * NN + n + 2) * LL + l];

        // ---- prefetch ALL operands for this step (48 x ds_read_b128) ----
        short8x Bv[16], A0v[16], A1v[16];
        #pragma unroll
        for (int d = 0; d < 16; ++d) {
            Bv[d]  = *(const short8x*)&psrc[baseB - 32 * d];
            A0v[d] = *(const short8x*)&pg[baseA - 32 * d];
            A1v[d] = *(const short8x*)&pg[baseA - 32 * d - 16];
        }

        // ---- fill g-table for step n+1 (independent buffer) under the
        //      MFMA shadow; uses pnext loaded one iteration ago ----
        if (n < NN - 1) fill_g((n + 1) & 1, pnext);

        // ---- 4 independent MFMA chains (d even/odd x 2 M-tiles) ----
        f32x4 acc0a = {0.f, 0.f, 0.f, 0.f}, acc0b = {0.f, 0.f, 0.f, 0.f};
        f32x4 acc1a = {0.f, 0.f, 0.f, 0.f}, acc1b = {0.f, 0.f, 0.f, 0.f};
        #pragma unroll
        for (int d = 0; d < 16; d += 2) {
            acc0a = __builtin_amdgcn_mfma_f32_16x16x32_bf16(A0v[d],     Bv[d],     acc0a, 0, 0, 0);
            acc1a = __builtin_amdgcn_mfma_f32_16x16x32_bf16(A1v[d],     Bv[d],     acc1a, 0, 0, 0);
            acc0b = __builtin_amdgcn_mfma_f32_16x16x32_bf16(A0v[d + 1], Bv[d + 1], acc0b, 0, 0, 0);
            acc1b = __builtin_amdgcn_mfma_f32_16x16x32_bf16(A1v[d + 1], Bv[d + 1], acc1b, 0, 0, 0);
        }
        f32x4 acc0 = acc0a + acc0b;
        f32x4 acc1 = acc1a + acc1b;

        // write Qn (bf16): lane holds rows 4qd..4qd+3 of both M-tiles, col nh
        *(uint2*)&pdst[dstw]      = uint2{pk_bf16(acc0.x, acc0.y), pk_bf16(acc0.z, acc0.w)};
        *(uint2*)&pdst[dstw + 16] = uint2{pk_bf16(acc1.x, acc1.y), pk_bf16(acc1.z, acc1.w)};

        // loss tap: lane 63 acc1.w == Qn[511] (row 31, col 15), fp32 precision
        float wgt = (n < NN - 1) ? (pnext + 1.f) : 1.f;   // pnext == pw[n+1]
        lossCh += wgt * acc1.w;
        pnext = pfut;
    }

    if (lane == 63) atomicAdd(out, lossCh);
}

extern "C" void kernel_launch(void* const* d_in, const int* in_sizes, int n_in,
                              void* d_out, int out_size, void* d_ws, size_t ws_size,
                              hipStream_t stream) {
    const float* pathloss = (const float*)d_in[0];
    const float* powers   = (const float*)d_in[1];
    float* outp = (float*)d_out;

    (void)hipMemsetAsync(d_out, 0, sizeof(float) * out_size, stream);
    outage_kernel<<<16 * LL, 64, 0, stream>>>(pathloss, powers, outp);
}